// Round 2
// baseline (445.917 us; speedup 1.0000x reference)
//
#include <hip/hip_runtime.h>
#include <hip/hip_fp16.h>

// VQ codebook argmin: N=32768 queries x K=8192 codes x D=256 fp32.
// Strategy: f16 hi/lo split (3 MFMA terms) => fp32-accurate dots on the
// 2.5PF matrix pipe; fused running argmin; XOR-swizzled LDS staging via
// global_load_lds(16B) to keep ds_read_b128 conflict-free.
//
// Scaling (exact powers of 2, argmin-invariant): z*=2^4, e*=2^15, so f16
// "lo" parts avoid fp16 subnormal flush. dist_scaled = 2^19*cb_sq - 2*acc.
//
// R1 fix: harness reads d_out as int32 (reference argmin dtype) -> write
// int indices, not float. R0's absmax 1.17e9 was float-bits-of-8189.

#define N_Q   32768
#define K_CB  8192
#define D_DIM 256

typedef _Float16 half8 __attribute__((ext_vector_type(8)));
typedef _Float16 half4 __attribute__((ext_vector_type(4)));
typedef float    f32x4 __attribute__((ext_vector_type(4)));

__device__ __forceinline__ void gl_lds16(const _Float16* g, _Float16* l) {
  __builtin_amdgcn_global_load_lds(
      (const __attribute__((address_space(1))) unsigned int*)g,
      (__attribute__((address_space(3))) unsigned int*)l, 16, 0, 0);
}

// ---------------- prep: z -> (hi,lo) f16, scale 2^4 ----------------
__global__ void vq_prep_z(const float* __restrict__ z,
                          _Float16* __restrict__ zh, _Float16* __restrict__ zl) {
  int i = blockIdx.x * 256 + threadIdx.x;          // 2,097,152 float4 groups
  float4 v = ((const float4*)z)[i];
  float xs[4] = {v.x * 16.0f, v.y * 16.0f, v.z * 16.0f, v.w * 16.0f};
  half4 h, l;
#pragma unroll
  for (int j = 0; j < 4; ++j) {
    _Float16 hj = (_Float16)xs[j];
    h[j] = hj;
    l[j] = (_Float16)(xs[j] - (float)hj);
  }
  ((half4*)zh)[i] = h;
  ((half4*)zl)[i] = l;
}

// ------- prep: codebook -> (hi,lo) f16 scale 2^15, plus 2^19*||e||^2 -------
__global__ void vq_prep_cb(const float* __restrict__ cb,
                           _Float16* __restrict__ eh, _Float16* __restrict__ el,
                           float* __restrict__ cbs) {
  int w = threadIdx.x >> 6, lane = threadIdx.x & 63;
  int code = blockIdx.x * 4 + w;                   // wave per code
  float4 v = ((const float4*)cb)[code * 64 + lane];
  float ss = v.x * v.x + v.y * v.y + v.z * v.z + v.w * v.w; // unscaled, like ref
  float xs[4] = {v.x * 32768.0f, v.y * 32768.0f, v.z * 32768.0f, v.w * 32768.0f};
  half4 h, l;
#pragma unroll
  for (int j = 0; j < 4; ++j) {
    _Float16 hj = (_Float16)xs[j];
    h[j] = hj;
    l[j] = (_Float16)(xs[j] - (float)hj);
  }
  ((half4*)eh)[code * 64 + lane] = h;
  ((half4*)el)[code * 64 + lane] = l;
#pragma unroll
  for (int off = 1; off < 64; off <<= 1) ss += __shfl_xor(ss, off);
  if (lane == 0) cbs[code] = ss * 524288.0f;       // 2^19 = (2^4 * 2^15)^... scale on dot
}

// ---------------- main: fused GEMM + running argmin ----------------
// Block: 256 thr = 4 waves (2x2), tile 128 queries x 128 codes per ct-iter.
// Grid: 256 query-tiles x 2 K-splits = 512 blocks (2/CU at 66KB LDS).
__global__ __launch_bounds__(256, 2)
void vq_main(const _Float16* __restrict__ zh, const _Float16* __restrict__ zl,
             const _Float16* __restrict__ eh, const _Float16* __restrict__ el,
             const float* __restrict__ cbs,
             unsigned long long* __restrict__ partials) {
  __shared__ __align__(16) _Float16 Ah[8192], Al[8192], Bh[8192], Bl[8192];
  __shared__ float    redD[2][128];
  __shared__ unsigned redC[2][128];

  const int tid  = threadIdx.x;
  const int lane = tid & 63;
  const int w    = tid >> 6;
  const int q    = lane & 15;
  const int quad = lane >> 4;
  const int wrow = (w >> 1) * 64;   // wave's query-row base in tile
  const int wcol = (w & 1) * 64;    // wave's code-col base in tile

  const int qt    = blockIdx.x >> 1;
  const int split = blockIdx.x & 1;
  const int q0    = qt * 128;
  const int c0    = split * 4096;

  // Fragment LDS offsets (halves). Layout: row*64 + (gb ^ (row&7))*8.
  int offA[4][2], offB[4][2];
#pragma unroll
  for (int mt = 0; mt < 4; ++mt) {
    int ra = wrow + mt * 16 + q;
    int rb = wcol + mt * 16 + q;
#pragma unroll
    for (int k2 = 0; k2 < 2; ++k2) {
      int gb = k2 * 4 + quad;
      offA[mt][k2] = ra * 64 + ((gb ^ (ra & 7)) << 3);
      offB[mt][k2] = rb * 64 + ((gb ^ (rb & 7)) << 3);
    }
  }

  float    rd[16];
  unsigned rc[16];
#pragma unroll
  for (int i = 0; i < 16; ++i) { rd[i] = 3.0e38f; rc[i] = 0u; }

  for (int ct = 0; ct < 32; ++ct) {
    const int crow0 = c0 + ct * 128;
    f32x4 acc[4][4];
#pragma unroll
    for (int mt = 0; mt < 4; ++mt)
#pragma unroll
      for (int nt = 0; nt < 4; ++nt)
        acc[mt][nt] = (f32x4){0.f, 0.f, 0.f, 0.f};

    for (int kk = 0; kk < 4; ++kk) {
      const int kcol = kk * 64;
      __syncthreads();  // WAR: previous iter's LDS reads done
#pragma unroll
      for (int c = 0; c < 4; ++c) {
        int bi   = (w * 4 + c) * 64 + lane;  // 16B-block index in tile
        int row  = bi >> 3;
        int gb   = (bi & 7) ^ (row & 7);     // swizzle on GLOBAL side
        int goff = row * 256 + kcol + gb * 8;
        int ldst = (w * 4 + c) * 512;        // wave-uniform LDS chunk base
        gl_lds16(zh + (size_t)q0 * 256 + goff,    &Ah[ldst]);
        gl_lds16(zl + (size_t)q0 * 256 + goff,    &Al[ldst]);
        gl_lds16(eh + (size_t)crow0 * 256 + goff, &Bh[ldst]);
        gl_lds16(el + (size_t)crow0 * 256 + goff, &Bl[ldst]);
      }
      __syncthreads();  // includes vmcnt(0): staged data visible

#pragma unroll
      for (int k2 = 0; k2 < 2; ++k2) {
        half8 ahf[4], alf[4], bhf[4], blf[4];
#pragma unroll
        for (int i = 0; i < 4; ++i) {
          ahf[i] = *(const half8*)&Ah[offA[i][k2]];
          alf[i] = *(const half8*)&Al[offA[i][k2]];
          bhf[i] = *(const half8*)&Bh[offB[i][k2]];
          blf[i] = *(const half8*)&Bl[offB[i][k2]];
        }
#pragma unroll
        for (int mt = 0; mt < 4; ++mt)
#pragma unroll
          for (int nt = 0; nt < 4; ++nt) {
            acc[mt][nt] = __builtin_amdgcn_mfma_f32_16x16x32_f16(ahf[mt], bhf[nt], acc[mt][nt], 0, 0, 0);
            acc[mt][nt] = __builtin_amdgcn_mfma_f32_16x16x32_f16(ahf[mt], blf[nt], acc[mt][nt], 0, 0, 0);
            acc[mt][nt] = __builtin_amdgcn_mfma_f32_16x16x32_f16(alf[mt], bhf[nt], acc[mt][nt], 0, 0, 0);
          }
      }
    }

    // Epilogue: dist = 2^19*cb_sq - 2*acc; running (min,idx) per row.
    const int cb0 = crow0 + wcol + q;
    float cbsv[4];
#pragma unroll
    for (int nt = 0; nt < 4; ++nt) cbsv[nt] = cbs[cb0 + nt * 16];
#pragma unroll
    for (int mt = 0; mt < 4; ++mt)
#pragma unroll
      for (int r = 0; r < 4; ++r) {
        float d = fmaf(-2.0f, acc[mt][0][r], cbsv[0]);
        unsigned cidx = (unsigned)cb0;
#pragma unroll
        for (int nt = 1; nt < 4; ++nt) {
          float dn = fmaf(-2.0f, acc[mt][nt][r], cbsv[nt]);
          if (dn < d) { d = dn; cidx = (unsigned)(cb0 + nt * 16); }  // strict <: first-index ties
        }
        int ri = mt * 4 + r;
        if (d < rd[ri]) { rd[ri] = d; rc[ri] = cidx; }
      }
  }

  // Cross-lane (16 codes) then cross-wave (2 col-halves) reduce.
#pragma unroll
  for (int ri = 0; ri < 16; ++ri) {
    float d = rd[ri]; unsigned cidx = rc[ri];
#pragma unroll
    for (int off = 1; off < 16; off <<= 1) {
      float od = __shfl_xor(d, off);
      unsigned oc = __shfl_xor(cidx, off);
      if (od < d || (od == d && oc < cidx)) { d = od; cidx = oc; }
    }
    if (q == 0) {
      int row = wrow + (ri >> 2) * 16 + quad * 4 + (ri & 3);
      redD[w & 1][row] = d;
      redC[w & 1][row] = cidx;
    }
  }
  __syncthreads();
  if (tid < 128) {
    float d0 = redD[0][tid]; unsigned cc0 = redC[0][tid];
    float d1 = redD[1][tid]; unsigned cc1 = redC[1][tid];
    if (d1 < d0 || (d1 == d0 && cc1 < cc0)) { d0 = d1; cc0 = cc1; }
    unsigned u = __float_as_uint(d0);
    u = (u & 0x80000000u) ? ~u : (u | 0x80000000u);  // orderable float
    partials[(size_t)split * N_Q + q0 + tid] = ((unsigned long long)u << 32) | cc0;
  }
}

// ---------------- final: combine splits, write INT32 indices ----------------
__global__ void vq_final(const unsigned long long* __restrict__ partials,
                         int* __restrict__ out) {
  int i = blockIdx.x * 256 + threadIdx.x;  // 32768
  unsigned long long a = partials[i], b = partials[(size_t)N_Q + i];
  unsigned long long m = (b < a) ? b : a;  // equal dist -> lower code (low 32b)
  out[i] = (int)(unsigned)(m & 0xffffffffull);
}

extern "C" void kernel_launch(void* const* d_in, const int* in_sizes, int n_in,
                              void* d_out, int out_size, void* d_ws, size_t ws_size,
                              hipStream_t stream) {
  const float* z  = (const float*)d_in[0];   // [32,32,32,256] fp32
  const float* cb = (const float*)d_in[1];   // [8192,256] fp32
  char* ws = (char*)d_ws;
  // ws layout (~40.6 MB): zh 16M | zl 16M | eh 4M | el 4M | cbs 32K | partials 512K
  _Float16* zh = (_Float16*)(ws);
  _Float16* zl = (_Float16*)(ws + (size_t)16 * 1024 * 1024);
  _Float16* eh = (_Float16*)(ws + (size_t)32 * 1024 * 1024);
  _Float16* el = (_Float16*)(ws + (size_t)36 * 1024 * 1024);
  float*    cbs = (float*)(ws + (size_t)40 * 1024 * 1024);
  unsigned long long* partials =
      (unsigned long long*)(ws + (size_t)40 * 1024 * 1024 + 65536);

  hipLaunchKernelGGL(vq_prep_z,  dim3(8192), dim3(256), 0, stream, z, zh, zl);
  hipLaunchKernelGGL(vq_prep_cb, dim3(2048), dim3(256), 0, stream, cb, eh, el, cbs);
  hipLaunchKernelGGL(vq_main,    dim3(512),  dim3(256), 0, stream,
                     zh, zl, eh, el, cbs, partials);
  hipLaunchKernelGGL(vq_final,   dim3(128),  dim3(256), 0, stream,
                     partials, (int*)d_out);
}